// Round 3
// baseline (42.861 us; speedup 1.0000x reference)
//
#include <hip/hip_runtime.h>

#define WSZ    64
#define BLOCK  256
#define CHUNK  16
#define PAD    (CHUNK + 1)      // 17: coprime with 32 -> conflict-free per-row LDS reads
#define NCHUNK (WSZ / CHUNK)

// ---------------------------------------------------------------------------
// Writer kernel: fold RZ(th1)*RY(th0) into an 8-coefficient 3x3 (Bloch) matrix
// per step, shared by all rows. Runs once per launch (1 block, 64 threads).
// Layout per step t (32B aligned): [m00 m01 m02 m10 m11 m12 m20 m22]
// ---------------------------------------------------------------------------
__global__ void coef_kernel(const float* __restrict__ theta, float* __restrict__ coef) {
    int t = threadIdx.x;
    if (t < WSZ) {
        float a = theta[2 * t + 0];
        float b = theta[2 * t + 1];
        float sa = sinf(a), ca = cosf(a);
        float sb = sinf(b), cb = cosf(b);
        float4* c4 = reinterpret_cast<float4*>(coef);
        c4[2 * t + 0] = make_float4(cb * ca, -sb, cb * sa, sb * ca);
        c4[2 * t + 1] = make_float4(cb, sb * sa, -sa, ca);
    }
}

__global__ __launch_bounds__(BLOCK) void sq_main(
    const float* __restrict__ x,
    const float* __restrict__ coef,
    const float* __restrict__ w,
    const float* __restrict__ bias,
    float* __restrict__ out)
{
    __shared__ float xs[BLOCK * PAD];   // 17408 B -> 8 blocks/CU, 32 waves/CU

    const int tid = threadIdx.x;
    const int tlo = tid & 3;            // float4 slot within a row's 16-col chunk
    const int thi = tid >> 2;           // base row (0..63)
    const size_t row0 = (size_t)blockIdx.x * BLOCK;
    const float* xblk = x + row0 * WSZ;
    const float INV2PI = 0.15915494309189535f;   // v_sin/v_cos take revolutions

    // prefetch chunk 0 (wave covers 16 rows x 64B contiguous segments)
    float4 rcur[4], rnxt[4];
    #pragma unroll
    for (int j = 0; j < 4; ++j) {
        int rr = thi + j * 64;
        rcur[j] = *reinterpret_cast<const float4*>(xblk + (size_t)rr * WSZ + tlo * 4);
    }

    // Bloch vector, |0> -> (0,0,1)
    float vx = 0.0f, vy = 0.0f, vz = 1.0f;
    const int rbase = tid * PAD;

    #pragma unroll
    for (int c = 0; c < NCHUNK; ++c) {
        // issue next chunk's loads; they fly under this chunk's compute
        if (c < NCHUNK - 1) {
            #pragma unroll
            for (int j = 0; j < 4; ++j) {
                int rr = thi + j * 64;
                rnxt[j] = *reinterpret_cast<const float4*>(
                    xblk + (size_t)rr * WSZ + (c + 1) * CHUNK + tlo * 4);
            }
        }
        // stage current chunk to LDS, pre-scaled to revolutions
        #pragma unroll
        for (int j = 0; j < 4; ++j) {
            int rr = thi + j * 64;
            float* p = &xs[rr * PAD + tlo * 4];
            p[0] = rcur[j].x * INV2PI;
            p[1] = rcur[j].y * INV2PI;
            p[2] = rcur[j].z * INV2PI;
            p[3] = rcur[j].w * INV2PI;
        }
        __syncthreads();

        #pragma unroll
        for (int t = 0; t < CHUNK; ++t) {
            float r = xs[rbase + t];                    // conflict-free ds_read_b32
            float s  = __builtin_amdgcn_sinf(r);
            float co = __builtin_amdgcn_cosf(r);
            const float* cf = coef + c * (CHUNK * 8) + t * 8;  // uniform -> s_load
            float y1 = co * vy - s * vz;                // Rx(xt)
            float z1 = s * vy + co * vz;
            float nx = cf[0] * vx + cf[1] * y1 + cf[2] * z1;
            float ny = cf[3] * vx + cf[4] * y1 + cf[5] * z1;
            float nz = cf[6] * vx + cf[7] * z1;         // m21 == 0
            vx = nx; vy = ny; vz = nz;
        }
        __syncthreads();   // protect xs before next chunk's stores

        if (c < NCHUNK - 1) {
            #pragma unroll
            for (int j = 0; j < 4; ++j) rcur[j] = rnxt[j];
        }
    }

    out[row0 + tid] = vz * w[0] + bias[0];
}

extern "C" void kernel_launch(void* const* d_in, const int* in_sizes, int n_in,
                              void* d_out, int out_size, void* d_ws, size_t ws_size,
                              hipStream_t stream) {
    const float* x     = (const float*)d_in[0];
    const float* theta = (const float*)d_in[1];
    const float* w     = (const float*)d_in[2];
    const float* b     = (const float*)d_in[3];
    float* out  = (float*)d_out;
    float* coef = (float*)d_ws;          // needs 64*8*4 = 2048 B of scratch

    coef_kernel<<<1, 64, 0, stream>>>(theta, coef);

    int nrows = out_size;                // B = 524288 (divisible by 256)
    int grid  = (nrows + BLOCK - 1) / BLOCK;
    sq_main<<<grid, BLOCK, 0, stream>>>(x, coef, w, b, out);
}

// Round 4
// 38.798 us; speedup vs baseline: 1.1047x; 1.1047x over previous
//
#include <hip/hip_runtime.h>

#define WSZ    64
#define BLOCK  64
#define INV2PI 0.15915494309189535f   // v_sin/v_cos take revolutions

__global__ __launch_bounds__(BLOCK) void sq_main(
    const float* __restrict__ x,
    const float* __restrict__ theta,
    const float* __restrict__ w,
    const float* __restrict__ bias,
    float* __restrict__ out)
{
    // x tile: [64 rows][16 float4-chunks], chunk position XOR-swizzled by row.
    // 16KB + 2KB coef -> 18KB/block -> 8 blocks/CU.
    __shared__ float4 xs4[WSZ * 16];
    __shared__ float4 tA[WSZ];   // (m00, m01, m02, m10) of Rz(b)*Ry(a) Bloch matrix
    __shared__ float4 tB[WSZ];   // (m11, m12, m20, m22); m21 == 0

    const int tid = threadIdx.x;                 // 0..63 == lane id (1 wave)
    const size_t row0 = (size_t)blockIdx.x * BLOCK;
    const float* xblk = x + row0 * WSZ;

    // ---- stage x tile: global->LDS DMA, 1KB per call, source pre-swizzled ----
    // LDS chunk q = i*64 + lane receives global chunk (row = q>>4, c4 = (q&15) ^ (row&7)).
    // Swizzle permutes 16B units within each 1KB stripe -> still perfectly coalesced.
#if defined(__has_builtin) && __has_builtin(__builtin_amdgcn_global_load_lds)
    #pragma unroll
    for (int i = 0; i < 16; ++i) {
        int row = i * 4 + (tid >> 4);
        int c4  = (tid & 15) ^ (row & 7);
        const float* src = xblk + row * WSZ + c4 * 4;
        __builtin_amdgcn_global_load_lds(
            (const __attribute__((address_space(1))) void*)src,
            (__attribute__((address_space(3))) void*)&xs4[i * 64], 16, 0, 0);
    }
#else
    #pragma unroll
    for (int i = 0; i < 16; ++i) {
        int row = i * 4 + (tid >> 4);
        int c4  = (tid & 15) ^ (row & 7);
        xs4[i * 64 + tid] = *reinterpret_cast<const float4*>(xblk + row * WSZ + c4 * 4);
    }
#endif

    // ---- per-step combined M = Rz(b)*Ry(a), hw trig (|theta|~0.01, err ~1e-6) ----
    {
        float a = theta[2 * tid + 0] * INV2PI;
        float b = theta[2 * tid + 1] * INV2PI;
        float sa = __builtin_amdgcn_sinf(a), ca = __builtin_amdgcn_cosf(a);
        float sb = __builtin_amdgcn_sinf(b), cb = __builtin_amdgcn_cosf(b);
        tA[tid] = make_float4(cb * ca, -sb, cb * sa, sb * ca);
        tB[tid] = make_float4(cb, sb * sa, -sa, ca);
    }

    __syncthreads();   // drains DMA (vmcnt) + coef writes (lgkmcnt)

    // ---- Bloch-vector evolution, |0> -> (0,0,1) ----
    float vx = 0.0f, vy = 0.0f, vz = 1.0f;
    const int rbase = tid * 16;
    const int rx    = tid & 7;

    #pragma unroll
    for (int c = 0; c < 16; ++c) {
        float4 xv = xs4[rbase + (c ^ rx)];       // conflict-free ds_read_b128
        #pragma unroll
        for (int j = 0; j < 4; ++j) {
            const int t = c * 4 + j;
            float r  = ((const float*)&xv)[j] * INV2PI;   // j compile-time
            float s  = __builtin_amdgcn_sinf(r);
            float co = __builtin_amdgcn_cosf(r);
            float4 A  = tA[t];                   // uniform -> LDS broadcast
            float4 Bv = tB[t];
            float y1 = co * vy - s * vz;         // Rx(x_t)
            float z1 = s  * vy + co * vz;
            float nx = A.x  * vx + A.y  * y1 + A.z  * z1;
            float ny = A.w  * vx + Bv.x * y1 + Bv.y * z1;
            float nz = Bv.z * vx + Bv.w * z1;    // m21 == 0
            vx = nx; vy = ny; vz = nz;
        }
    }

    out[row0 + tid] = vz * w[0] + bias[0];
}

extern "C" void kernel_launch(void* const* d_in, const int* in_sizes, int n_in,
                              void* d_out, int out_size, void* d_ws, size_t ws_size,
                              hipStream_t stream) {
    const float* x     = (const float*)d_in[0];
    const float* theta = (const float*)d_in[1];
    const float* w     = (const float*)d_in[2];
    const float* b     = (const float*)d_in[3];
    float* out = (float*)d_out;

    int nrows = out_size;                        // B = 524288
    int grid  = nrows / BLOCK;                   // 8192 blocks
    sq_main<<<grid, BLOCK, 0, stream>>>(x, theta, w, b, out);
}